// Round 1
// baseline (187.005 us; speedup 1.0000x reference)
//
#include <hip/hip_runtime.h>
#include <hip/hip_bf16.h>

#define HN 20
#define G4 80
#define EPSC 1e-5f

// ---------------- precompute kernel (runs once per launch, 1 block) --------
// ws layout (floats):
//   [0..79]    Ag   = (A - mean(A)) * g_x[0]
//   [80..159]  Cg   = (C - mean(C)) * g_x[0]
//   [160..239] K0   = be_x[0] + be_h[0] + b_ih[0] + b_hh[0]
//   [240..242] va, cov, vc (means over 80 of Ahat^2, Ahat*Chat, Chat^2)
//   [256..1855]  Wih1c (column-centered Wih[1], row-major 80x20)
//   [1856..3455] Whh1c (column-centered Whh[1])
//   [3456..3535] K1  = be_x[1] + be_h[1] + b_ih[1] + b_hh[1]
__global__ void ml_precompute(
    const float* __restrict__ W1,   // [20,1]
    const float* __restrict__ b1,   // [20]
    const float* __restrict__ Wih,  // [2,80,20]
    const float* __restrict__ Whh,  // [2,80,20]
    const float* __restrict__ b_ih, // [2,80]
    const float* __restrict__ b_hh, // [2,80]
    const float* __restrict__ g_x,  // [2,80]
    const float* __restrict__ be_x, // [2,80]
    const float* __restrict__ g_h,  // [2,80]
    const float* __restrict__ be_h, // [2,80]
    float* __restrict__ ws)
{
    __shared__ float A[G4], C[G4];
    __shared__ float cm_ih[HN], cm_hh[HN];
    __shared__ float stats[3];
    const int t = threadIdx.x;

    if (t < G4) {
        float a = 0.f, c = 0.f;
        for (int k = 0; k < HN; ++k) {
            float w = Wih[t * HN + k];
            a += w * W1[k];
            c += w * b1[k];
        }
        A[t] = a; C[t] = c;
    }
    if (t >= 128 && t < 128 + HN) {
        int k = t - 128;
        float s = 0.f;
        for (int j = 0; j < G4; ++j) s += Wih[1600 + j * HN + k];
        cm_ih[k] = s * (1.f / 80.f);
    }
    if (t >= 160 && t < 160 + HN) {
        int k = t - 160;
        float s = 0.f;
        for (int j = 0; j < G4; ++j) s += Whh[1600 + j * HN + k];
        cm_hh[k] = s * (1.f / 80.f);
    }
    __syncthreads();
    if (t == 0) {
        float am = 0.f, cm = 0.f;
        for (int j = 0; j < G4; ++j) { am += A[j]; cm += C[j]; }
        am *= (1.f / 80.f); cm *= (1.f / 80.f);
        float va = 0.f, cov = 0.f, vc = 0.f;
        for (int j = 0; j < G4; ++j) {
            float ah = A[j] - am, ch = C[j] - cm;
            va += ah * ah; cov += ah * ch; vc += ch * ch;
            A[j] = ah; C[j] = ch;
        }
        stats[0] = va * (1.f / 80.f);
        stats[1] = cov * (1.f / 80.f);
        stats[2] = vc * (1.f / 80.f);
    }
    __syncthreads();
    if (t < G4) {
        ws[t]       = A[t] * g_x[t];
        ws[80 + t]  = C[t] * g_x[t];
        ws[160 + t] = be_x[t] + be_h[t] + b_ih[t] + b_hh[t];
        ws[3456 + t] = be_x[80 + t] + be_h[80 + t] + b_ih[80 + t] + b_hh[80 + t];
    }
    if (t < 3) ws[240 + t] = stats[t];
    for (int idx = t; idx < 1600; idx += blockDim.x) {
        int k = idx % HN;
        ws[256 + idx]  = Wih[1600 + idx] - cm_ih[k];
        ws[1856 + idx] = Whh[1600 + idx] - cm_hh[k];
    }
}

// ---------------- main kernel: 1 thread per coordinate ---------------------
__device__ __forceinline__ float sigf(float x) {
    return __builtin_amdgcn_rcpf(1.f + __expf(-x));
}
__device__ __forceinline__ float tanhfast(float x) {
    return 1.f - 2.f * __builtin_amdgcn_rcpf(1.f + __expf(2.f * x));
}

__global__ __launch_bounds__(256, 2) void ml_main(
    const float* __restrict__ x_t,
    const float* __restrict__ ws,
    const float* __restrict__ g_x,  // [2,80]; layer1 at +80
    const float* __restrict__ g_h,  // [2,80]
    const float* __restrict__ g_c,  // [2,20]
    const float* __restrict__ be_c, // [2,20]
    const float* __restrict__ Wo,   // [20]
    const float* __restrict__ bo,   // [1]
    float* __restrict__ out, int n)
{
    const int i = blockIdx.x * blockDim.x + threadIdx.x;
    if (i >= n) return;
    const float x = x_t[i];

    const float* __restrict__ Ag   = ws;
    const float* __restrict__ Cg   = ws + 80;
    const float* __restrict__ K0   = ws + 160;
    const float* __restrict__ Wihc = ws + 256;
    const float* __restrict__ Whhc = ws + 1856;
    const float* __restrict__ K1   = ws + 3456;

    const float va = ws[240], cov = ws[241], vc = ws[242];
    const float rs0 = __builtin_amdgcn_rsqf(fmaf(va * x, x, fmaf(2.f * cov, x, vc)) + EPSC);

    // ---- layer 0 (f-gate dead: cx=0) ----
    float c0[HN], h0[HN];
    float mu = 0.f;
#pragma unroll
    for (int k = 0; k < HN; ++k) {
        float gi = fmaf(fmaf(Ag[k], x, Cg[k]), rs0, K0[k]);
        float gg = fmaf(fmaf(Ag[40 + k], x, Cg[40 + k]), rs0, K0[40 + k]);
        float c = sigf(gi) * tanhfast(gg);
        c0[k] = c; mu += c;
    }
    mu *= 0.05f;
    float var = 0.f;
#pragma unroll
    for (int k = 0; k < HN; ++k) { float d = c0[k] - mu; var = fmaf(d, d, var); }
    const float rsc = __builtin_amdgcn_rsqf(fmaf(var, 0.05f, EPSC));
#pragma unroll
    for (int k = 0; k < HN; ++k) {
        float go = fmaf(fmaf(Ag[60 + k], x, Cg[60 + k]), rs0, K0[60 + k]);
        float tn = tanhfast(fmaf((c0[k] - mu) * rsc, g_c[k], be_c[k]));
        h0[k] = sigf(go) * tn;
    }

    // ---- layer 1: two 20->80 matvecs with column-centered weights ----
    float u[G4], v[G4];
    float su = 0.f, sv = 0.f;
#pragma unroll
    for (int j = 0; j < G4; ++j) {
        float uu = 0.f, vv = 0.f;
#pragma unroll
        for (int k = 0; k < HN; ++k) {
            uu = fmaf(Wihc[j * HN + k], h0[k], uu);
            vv = fmaf(Whhc[j * HN + k], h0[k], vv);
        }
        u[j] = uu; v[j] = vv;
        su = fmaf(uu, uu, su); sv = fmaf(vv, vv, sv);
    }
    const float rsu = __builtin_amdgcn_rsqf(fmaf(su, 0.0125f, EPSC));
    const float rsv = __builtin_amdgcn_rsqf(fmaf(sv, 0.0125f, EPSC));

    float c1[HN];
    float mu1 = 0.f;
#pragma unroll
    for (int k = 0; k < HN; ++k) {
        float gi = fmaf(u[k] * rsu,      g_x[80 + k],  fmaf(v[k] * rsv,      g_h[80 + k],  K1[k]));
        float gf = fmaf(u[20 + k] * rsu, g_x[100 + k], fmaf(v[20 + k] * rsv, g_h[100 + k], K1[20 + k])) + 1.0f;
        float gg = fmaf(u[40 + k] * rsu, g_x[120 + k], fmaf(v[40 + k] * rsv, g_h[120 + k], K1[40 + k]));
        float c = sigf(gf) * c0[k] + sigf(gi) * tanhfast(gg);
        c1[k] = c; mu1 += c;
    }
    mu1 *= 0.05f;
    float var1 = 0.f;
#pragma unroll
    for (int k = 0; k < HN; ++k) { float d = c1[k] - mu1; var1 = fmaf(d, d, var1); }
    const float rsc1 = __builtin_amdgcn_rsqf(fmaf(var1, 0.05f, EPSC));

    float acc = bo[0];
#pragma unroll
    for (int k = 0; k < HN; ++k) {
        float go = fmaf(u[60 + k] * rsu, g_x[140 + k], fmaf(v[60 + k] * rsv, g_h[140 + k], K1[60 + k]));
        float tn = tanhfast(fmaf((c1[k] - mu1) * rsc1, g_c[20 + k], be_c[20 + k]));
        acc = fmaf(sigf(go) * tn, Wo[k], acc);
    }
    out[i] = acc;
}

extern "C" void kernel_launch(void* const* d_in, const int* in_sizes, int n_in,
                              void* d_out, int out_size, void* d_ws, size_t ws_size,
                              hipStream_t stream) {
    const float* x_t  = (const float*)d_in[0];
    const float* W1   = (const float*)d_in[1];
    const float* b1   = (const float*)d_in[2];
    const float* Wih  = (const float*)d_in[3];
    const float* Whh  = (const float*)d_in[4];
    const float* b_ih = (const float*)d_in[5];
    const float* b_hh = (const float*)d_in[6];
    const float* g_x  = (const float*)d_in[7];
    const float* be_x = (const float*)d_in[8];
    const float* g_h  = (const float*)d_in[9];
    const float* be_h = (const float*)d_in[10];
    const float* g_c  = (const float*)d_in[11];
    const float* be_c = (const float*)d_in[12];
    const float* Wo   = (const float*)d_in[13];
    const float* bo   = (const float*)d_in[14];
    float* out = (float*)d_out;
    float* ws  = (float*)d_ws;
    const int n = in_sizes[0];

    hipLaunchKernelGGL(ml_precompute, dim3(1), dim3(256), 0, stream,
                       W1, b1, Wih, Whh, b_ih, b_hh, g_x, be_x, g_h, be_h, ws);
    const int blocks = (n + 255) / 256;
    hipLaunchKernelGGL(ml_main, dim3(blocks), dim3(256), 0, stream,
                       x_t, ws, g_x, g_h, g_c, be_c, Wo, bo, out, n);
}